// Round 9
// baseline (328.523 us; speedup 1.0000x reference)
//
#include <hip/hip_runtime.h>
#include <math.h>

// Problem constants (B=8, N=36, D=64)
#define NB    8
#define NNODE 36
#define NN2   1296     // 36*36
#define ND    64
#define NC    72       // 2*N constraints
#define KDIAG 1225.0   // (N-1)^2
#define EPSK  1e-5
#define CGMAX 32
#define PT64  21       // ceil(1296/64); lanes 0..15 own 21 elems, rest 20

// ---------------------------------------------------------------------------
// Wave-wide (64-lane) fp64 all-reduce sum via butterfly shuffle — no LDS,
// no barriers; every lane ends with the full sum (uniform => uniform branches)
// ---------------------------------------------------------------------------
__device__ __forceinline__ double wave_allsum(double v) {
#pragma unroll
  for (int m = 32; m > 0; m >>= 1) v += __shfl_xor(v, m);
  return v;
}

// ---------------------------------------------------------------------------
// Kernel 1: normalize over node axis, linear (W_cg,b_cg), relu, then
// PT[b][t][s] = Mp[b][s][t] = h1[b,s,:]·h2[b,t,:]
// PT flat (t-major) is simultaneously the KKT primal rhs Mpp.
// ---------------------------------------------------------------------------
__global__ __launch_bounds__(256) void k_feat_p(const float* __restrict__ emb1,
                                                const float* __restrict__ emb2,
                                                const float* __restrict__ Wcg,
                                                const float* __restrict__ bcg,
                                                float* __restrict__ PT) {
  const int b = blockIdx.x;
  __shared__ float e1[NNODE * ND], e2[NNODE * ND];
  __shared__ float h1[NNODE * ND], h2[NNODE * ND];
  __shared__ float Ws[ND * ND];
  __shared__ float nrm1[ND], nrm2[ND];
  const int tid = threadIdx.x;

  for (int i = tid; i < NNODE * ND; i += 256) {
    e1[i] = emb1[b * NNODE * ND + i];
    e2[i] = emb2[b * NNODE * ND + i];
  }
  for (int i = tid; i < ND * ND; i += 256) Ws[i] = Wcg[i];
  __syncthreads();

  // per-(b,d) L2 norm over the 36 nodes, clipped at 1e-12 (ref: clip(norm,1e-12))
  if (tid < ND) {
    float s = 0.f;
    for (int n = 0; n < NNODE; ++n) { float v = e1[n * ND + tid]; s += v * v; }
    nrm1[tid] = fmaxf(sqrtf(s), 1e-12f);
  } else if (tid < 2 * ND) {
    int d = tid - ND;
    float s = 0.f;
    for (int n = 0; n < NNODE; ++n) { float v = e2[n * ND + d]; s += v * v; }
    nrm2[d] = fmaxf(sqrtf(s), 1e-12f);
  }
  __syncthreads();

  for (int i = tid; i < NNODE * ND; i += 256) {
    int d = i & (ND - 1);
    e1[i] /= nrm1[d];
    e2[i] /= nrm2[d];
  }
  __syncthreads();

  // h[n][i] = relu( sum_d e[n][d] * W[i][d] + b[i] )
  for (int o = tid; o < NNODE * ND; o += 256) {
    int n = o >> 6, i = o & (ND - 1);
    float a1 = bcg[i], a2 = bcg[i];
    for (int d = 0; d < ND; ++d) {
      float w = Ws[i * ND + d];
      a1 += e1[n * ND + d] * w;
      a2 += e2[n * ND + d] * w;
    }
    h1[o] = fmaxf(a1, 0.f);
    h2[o] = fmaxf(a2, 0.f);
  }
  __syncthreads();

  // PT[t][s] = sum_d h1[s][d]*h2[t][d]
  for (int o = tid; o < NN2; o += 256) {
    int t = o / NNODE, s = o % NNODE;
    float a = 0.f;
    for (int d = 0; d < ND; ++d) a += h1[s * ND + d] * h2[t * ND + d];
    PT[b * NN2 + o] = a;
  }
}

// ---------------------------------------------------------------------------
// Kernel 2: SINGLE-WAVE (64-thread) fp64 CG per (batch, rhs) on
// Q = 1225*I - M with the O(n^2) structured matvec:
//   (Mx)[t][s] = 0.5*( PT[t][s]*(tot - R[t] - C[s] + x[t][s])
//                     + (Wtot - WR[t] - WC[s] + PT[t][s]*x[t][s]) )
// All reductions are wave shuffles (no barriers); the only __syncthreads are
// single-wave-cheap LDS-ordering fences for pv (2 per CG iteration). This
// removes the ~8 four-wave barriers/iter that dominated the 256-thread k_cg.
// Epilogue emits A*x = Schur column (rid<72) or A*y - 1 (rid==72) to Scols.
// ---------------------------------------------------------------------------
__global__ __launch_bounds__(64) void k_cg(const float* __restrict__ PT,
                                           float* __restrict__ Z,
                                           double* __restrict__ Y,
                                           double* __restrict__ Scols) {
  const int b = blockIdx.x / 73;
  const int rid = blockIdx.x % 73;
  const int lane = threadIdx.x;

  __shared__ float pt[NN2];
  __shared__ double pv[NN2];
  __shared__ double R[NNODE], C[NNODE], WR[NNODE], WC[NNODE];

  double xl[PT64], rl[PT64], al[PT64];

  for (int i = lane; i < NN2; i += 64) pt[i] = PT[b * NN2 + i];
  __syncthreads();

  double loc = 0.0;
#pragma unroll
  for (int k = 0; k < PT64; ++k) {
    int i = lane + 64 * k;
    if (i < NN2) {
      int t = i / NNODE, s = i % NNODE;
      double rhs;
      if (rid == 72)      rhs = (double)pt[i];
      else if (rid < 36)  rhs = (s == rid) ? 1.0 : 0.0;
      else                rhs = (t == rid - 36) ? 1.0 : 0.0;
      xl[k] = 0.0; rl[k] = rhs; pv[i] = rhs;
      loc += rhs * rhs;
    }
  }
  __syncthreads();
  double rr = wave_allsum(loc);
  const double rr0 = rr;

  for (int it = 0; it < CGMAX; ++it) {
    // ---- row/col sums of pv and W = pt.*pv (72 tasks over 64 lanes) ----
    for (int task = lane; task < 2 * NNODE; task += 64) {
      if (task < NNODE) {
        int t = task; double r0 = 0.0, wr0 = 0.0;
        for (int s = 0; s < NNODE; ++s) {
          double v = pv[t * NNODE + s];
          r0 += v; wr0 += (double)pt[t * NNODE + s] * v;
        }
        R[t] = r0; WR[t] = wr0;
      } else {
        int s = task - NNODE; double c0 = 0.0, wc0 = 0.0;
        for (int t = 0; t < NNODE; ++t) {
          double v = pv[t * NNODE + s];
          c0 += v; wc0 += (double)pt[t * NNODE + s] * v;
        }
        C[s] = c0; WC[s] = wc0;
      }
    }
    __syncthreads();
    double tot  = wave_allsum(lane < NNODE ? R[lane]  : 0.0);
    double wtot = wave_allsum(lane < NNODE ? WR[lane] : 0.0);

    // ---- ap = Q*pv (registers), pap = pv.ap ----
    double locpap = 0.0;
#pragma unroll
    for (int k = 0; k < PT64; ++k) {
      int i = lane + 64 * k;
      if (i < NN2) {
        int t = i / NNODE, s = i % NNODE;
        double pval = pv[i], ptv = (double)pt[i];
        double sig1 = tot  - R[t]  - C[s]  + pval;
        double sig2 = wtot - WR[t] - WC[s] + ptv * pval;
        double q = KDIAG * pval - 0.5 * (ptv * sig1 + sig2);
        al[k] = q;
        locpap += pval * q;
      }
    }
    double pap = wave_allsum(locpap);
    double alpha = rr / pap;

    double locrr = 0.0;
#pragma unroll
    for (int k = 0; k < PT64; ++k) {
      int i = lane + 64 * k;
      if (i < NN2) {
        xl[k] += alpha * pv[i];
        double rn = rl[k] - alpha * al[k];
        rl[k] = rn;
        locrr += rn * rn;
      }
    }
    double rrn = wave_allsum(locrr);
    double beta = rrn / rr;
    rr = rrn;
    // rel. residual 1e-9 — plenty vs the reference's own fp32-LU noise.
    // wave_allsum is lane-uniform => uniform exit.
    if (rr < 1e-18 * rr0 || rr < 1e-30) break;
#pragma unroll
    for (int k = 0; k < PT64; ++k) {
      int i = lane + 64 * k;
      if (i < NN2) pv[i] = rl[k] + beta * pv[i];
    }
    __syncthreads();
  }

  // ---- store solution ----
  if (rid == 72) {
#pragma unroll
    for (int k = 0; k < PT64; ++k) {
      int i = lane + 64 * k;
      if (i < NN2) Y[b * NN2 + i] = xl[k];
    }
  } else {
#pragma unroll
    for (int k = 0; k < PT64; ++k) {
      int i = lane + 64 * k;
      if (i < NN2) Z[((size_t)b * NC + rid) * NN2 + i] = (float)xl[k];
    }
  }

  // ---- epilogue: A*x -> Schur column (or A*y - 1 for rid==72) ----
  __syncthreads();   // CG-loop reads of pv done
#pragma unroll
  for (int k = 0; k < PT64; ++k) {
    int i = lane + 64 * k;
    if (i < NN2) pv[i] = xl[k];
  }
  __syncthreads();
  for (int task = lane; task < 2 * NNODE; task += 64) {
    if (task < NNODE) {              // S rows 36..71: first-index (row) sums
      double r0 = 0.0;
      for (int s = 0; s < NNODE; ++s) r0 += pv[task * NNODE + s];
      if (rid == 72) r0 -= 1.0;
      Scols[((size_t)b * 73 + rid) * NC + NNODE + task] = r0;
    } else {                         // S rows 0..35: second-index (col) sums
      int s = task - NNODE;
      double c0 = 0.0;
      for (int t = 0; t < NNODE; ++t) c0 += pv[t * NNODE + s];
      if (rid == 72) c0 -= 1.0;
      Scols[((size_t)b * 73 + rid) * NC + s] = c0;
    }
  }
}

// ---------------------------------------------------------------------------
// Kernel 3: SINGLE-WAVE right-looking fp64 Cholesky of S + eps*I (72x72)
// and triangular solves -> LAM.  Diagonal is pre-updated (right-looking), so
// sqrt/div are computed redundantly on all lanes via LDS broadcast — no
// serial tid==0 phases; 2 cheap single-wave barriers per factor step,
// 1 per trisolve step (vs ~432 four-wave barriers before: 113 us).
// S is symmetric, so Scols (column-major) can be loaded flat as row-major.
// ---------------------------------------------------------------------------
__global__ __launch_bounds__(64) void k_chol(const double* __restrict__ Scols,
                                             double* __restrict__ LAM) {
  const int b = blockIdx.x;
  const int lane = threadIdx.x;
  __shared__ double S[NC * NC];
  __shared__ double Lc[NC];
  __shared__ double lam[NC];

  for (int o = lane; o < NC * NC; o += 64) {
    double v = Scols[(size_t)b * 73 * NC + o];
    if (o % (NC + 1) == 0) v += EPSK;
    S[o] = v;
  }
  for (int i = lane; i < NC; i += 64)
    lam[i] = Scols[((size_t)b * 73 + 72) * NC + i];
  __syncthreads();

  // right-looking Cholesky (lower); upper triangle receives junk (never read)
  for (int j = 0; j < NC; ++j) {
    double inv = 1.0 / sqrt(S[j * NC + j]);   // all lanes: LDS broadcast
    for (int i = j + lane; i < NC; i += 64) {
      double v = S[i * NC + j] * inv;          // i==j -> diag = sqrt(d)
      Lc[i] = v;
      S[i * NC + j] = v;
    }
    __syncthreads();
    // rank-1 trailing update, 8x8 lane tiling over the trailing square
    {
      int a = lane >> 3, q = lane & 7;
      for (int i = j + 1 + a; i < NC; i += 8) {
        double li = Lc[i];
        for (int k = j + 1 + q; k < NC; k += 8)
          S[i * NC + k] -= li * Lc[k];
      }
    }
    __syncthreads();
  }

  // forward: L u = rhs (column sweep)
  for (int j = 0; j < NC; ++j) {
    double u = lam[j] / S[j * NC + j];        // all lanes (broadcast)
    if (lane == 0) lam[j] = u;
    for (int i = j + 1 + lane; i < NC; i += 64) lam[i] -= S[i * NC + j] * u;
    __syncthreads();
  }
  // backward: L^T lam = u (column sweep: lam[k] -= L[j][k]*lam_j, k<j)
  for (int j = NC - 1; j >= 0; --j) {
    double u = lam[j] / S[j * NC + j];
    if (lane == 0) lam[j] = u;
    for (int k = lane; k < j; k += 64) lam[k] -= S[j * NC + k] * u;
    __syncthreads();
  }
  for (int i = lane; i < NC; i += 64) LAM[b * NC + i] = lam[i];
}

// ---------------------------------------------------------------------------
// Kernel 4: x = y - Z*lambda (coalesced Z reads), clamp [0,1],
// out[b][i][j] = softmax_j(1000 * x[j][i]).
// ---------------------------------------------------------------------------
__global__ __launch_bounds__(256) void k_xout(const float* __restrict__ Z,
                                              const double* __restrict__ Y,
                                              const double* __restrict__ LAM,
                                              float* __restrict__ out) {
  const int b = blockIdx.x;
  const int tid = threadIdx.x;
  __shared__ double lam[NC];
  __shared__ float xm[NN2];
  __shared__ float mrow[NNODE], irow[NNODE];

  if (tid < NC) lam[tid] = LAM[b * NC + tid];
  __syncthreads();

  const float* Zb = Z + (size_t)b * NC * NN2;
  const double* yb = Y + (size_t)b * NN2;

  // x = y - Z*lambda: thread -> element i (consecutive => coalesced over j)
  for (int i = tid; i < NN2; i += 256) {
    double acc = yb[i];
#pragma unroll 8
    for (int j = 0; j < NC; ++j) acc -= (double)Zb[j * NN2 + i] * lam[j];
    float v = (float)acc;
    xm[i] = fminf(fmaxf(v, 0.f), 1.f);
  }
  __syncthreads();

  // per-output-row i: max and softmax denominator over j (column i of xm)
  if (tid < NNODE) {
    float m = -1e30f;
    for (int j = 0; j < NNODE; ++j) m = fmaxf(m, xm[j * NNODE + tid]);
    float sum = 0.f;
    for (int j = 0; j < NNODE; ++j) sum += expf(1000.f * (xm[j * NNODE + tid] - m));
    mrow[tid] = m;
    irow[tid] = 1.f / sum;
  }
  __syncthreads();

  for (int o = tid; o < NN2; o += 256) {
    int i = o / NNODE, j = o % NNODE;
    out[(size_t)b * NN2 + o] = expf(1000.f * (xm[j * NNODE + i] - mrow[i])) * irow[i];
  }
}

// ---------------------------------------------------------------------------
extern "C" void kernel_launch(void* const* d_in, const int* in_sizes, int n_in,
                              void* d_out, int out_size, void* d_ws, size_t ws_size,
                              hipStream_t stream) {
  (void)in_sizes; (void)n_in; (void)out_size; (void)ws_size;
  const float* emb1 = (const float*)d_in[0];
  const float* emb2 = (const float*)d_in[1];
  const float* Wcg  = (const float*)d_in[2];
  const float* bcg  = (const float*)d_in[3];
  float* out = (float*)d_out;

  char* ws = (char*)d_ws;
  float*  PT    = (float*) (ws);                 // 8*1296 f32          = 41472 B
  float*  Z     = (float*) (ws + 41472);         // 8*72*1296 f32       = 2985984 B
  double* Y     = (double*)(ws + 3027456);       // 8*1296 f64          = 82944 B
  double* Scols = (double*)(ws + 3110400);       // 8*73*72 f64         = 336384 B
  double* LAM   = (double*)(ws + 3446784);       // 8*72 f64            = 4608 B

  hipLaunchKernelGGL(k_feat_p, dim3(NB),      dim3(256), 0, stream, emb1, emb2, Wcg, bcg, PT);
  hipLaunchKernelGGL(k_cg,     dim3(NB * 73), dim3(64),  0, stream, PT, Z, Y, Scols);
  hipLaunchKernelGGL(k_chol,   dim3(NB),      dim3(64),  0, stream, Scols, LAM);
  hipLaunchKernelGGL(k_xout,   dim3(NB),      dim3(256), 0, stream, Z, Y, LAM, out);
}

// Round 12
// 144.168 us; speedup vs baseline: 2.2788x; 2.2788x over previous
//
#include <hip/hip_runtime.h>
#include <math.h>

// Problem constants (B=8, N=36, D=64)
#define NB    8
#define NNODE 36
#define NN2   1296     // 36*36
#define ND    64
#define NC    72       // 2*N constraints
#define KDIAG 1225.0   // (N-1)^2
#define EPSK  1e-5
#define CGMAX 32
#define PERTHREAD 6    // ceil(1296/256)
#define SROW  73       // padded LDS row stride for S (breaks 32-way bank conflict)
#define CGSMAX 48      // Schur-CG max iters (kappa<=5.9 -> ~27 expected)

// ---------------------------------------------------------------------------
// Block-wide fp64 sum reduction (256 threads = 4 waves of 64)
// ---------------------------------------------------------------------------
__device__ __forceinline__ double blk_reduce(double v, double* red, double* out) {
#pragma unroll
  for (int off = 32; off > 0; off >>= 1) v += __shfl_down(v, off);
  if ((threadIdx.x & 63) == 0) red[threadIdx.x >> 6] = v;
  __syncthreads();
  if (threadIdx.x == 0) *out = red[0] + red[1] + red[2] + red[3];
  __syncthreads();
  return *out;
}

// ---------------------------------------------------------------------------
// Kernel 1: normalize over node axis, linear (W_cg,b_cg), relu, then
// PT[b][t][s] = Mp[b][s][t] = h1[b,s,:]·h2[b,t,:]
// PT flat (t-major) is simultaneously the KKT primal rhs Mpp.
// ---------------------------------------------------------------------------
__global__ __launch_bounds__(256) void k_feat_p(const float* __restrict__ emb1,
                                                const float* __restrict__ emb2,
                                                const float* __restrict__ Wcg,
                                                const float* __restrict__ bcg,
                                                float* __restrict__ PT) {
  const int b = blockIdx.x;
  __shared__ float e1[NNODE * ND], e2[NNODE * ND];
  __shared__ float h1[NNODE * ND], h2[NNODE * ND];
  __shared__ float Ws[ND * ND];
  __shared__ float nrm1[ND], nrm2[ND];
  const int tid = threadIdx.x;

  for (int i = tid; i < NNODE * ND; i += 256) {
    e1[i] = emb1[b * NNODE * ND + i];
    e2[i] = emb2[b * NNODE * ND + i];
  }
  for (int i = tid; i < ND * ND; i += 256) Ws[i] = Wcg[i];
  __syncthreads();

  // per-(b,d) L2 norm over the 36 nodes, clipped at 1e-12 (ref: clip(norm,1e-12))
  if (tid < ND) {
    float s = 0.f;
    for (int n = 0; n < NNODE; ++n) { float v = e1[n * ND + tid]; s += v * v; }
    nrm1[tid] = fmaxf(sqrtf(s), 1e-12f);
  } else if (tid < 2 * ND) {
    int d = tid - ND;
    float s = 0.f;
    for (int n = 0; n < NNODE; ++n) { float v = e2[n * ND + d]; s += v * v; }
    nrm2[d] = fmaxf(sqrtf(s), 1e-12f);
  }
  __syncthreads();

  for (int i = tid; i < NNODE * ND; i += 256) {
    int d = i & (ND - 1);
    e1[i] /= nrm1[d];
    e2[i] /= nrm2[d];
  }
  __syncthreads();

  // h[n][i] = relu( sum_d e[n][d] * W[i][d] + b[i] )
  for (int o = tid; o < NNODE * ND; o += 256) {
    int n = o >> 6, i = o & (ND - 1);
    float a1 = bcg[i], a2 = bcg[i];
    for (int d = 0; d < ND; ++d) {
      float w = Ws[i * ND + d];
      a1 += e1[n * ND + d] * w;
      a2 += e2[n * ND + d] * w;
    }
    h1[o] = fmaxf(a1, 0.f);
    h2[o] = fmaxf(a2, 0.f);
  }
  __syncthreads();

  // PT[t][s] = sum_d h1[s][d]*h2[t][d]
  for (int o = tid; o < NN2; o += 256) {
    int t = o / NNODE, s = o % NNODE;
    float a = 0.f;
    for (int d = 0; d < ND; ++d) a += h1[s * ND + d] * h2[t * ND + d];
    PT[b * NN2 + o] = a;
  }
}

// ---------------------------------------------------------------------------
// Kernel 2 (round-7 verified 256-thread version): one workgroup per
// (batch, rhs) — fp64 CG on Q = 1225*I - M, O(n^2) structured matvec:
//   (Mx)[t][s] = 0.5*( PT[t][s]*(tot - R[t] - C[s] + x[t][s])
//                     + (Wtot - WR[t] - WC[s] + PT[t][s]*x[t][s]) )
// Epilogue: A*x -> Schur column (rid<72) or A*y - 1 (rid==72) into Scols.
// ---------------------------------------------------------------------------
__global__ __launch_bounds__(256) void k_cg(const float* __restrict__ PT,
                                            float* __restrict__ Z,
                                            double* __restrict__ Y,
                                            double* __restrict__ Scols) {
  const int b = blockIdx.x / 73;
  const int rid = blockIdx.x % 73;
  const int tid = threadIdx.x;

  __shared__ float pt[NN2];
  __shared__ double pv[NN2];
  __shared__ double R[NNODE], C[NNODE], WR[NNODE], WC[NNODE];
  __shared__ double totW[2];
  __shared__ double red[4], s_pap, s_rr;

  double xl[PERTHREAD], rl[PERTHREAD], al[PERTHREAD];

  for (int i = tid; i < NN2; i += 256) pt[i] = PT[b * NN2 + i];
  __syncthreads();

#pragma unroll
  for (int k = 0; k < PERTHREAD; ++k) {
    int i = tid + 256 * k;
    if (i >= NN2) break;
    int t = i / NNODE, s = i % NNODE;
    double rhs;
    if (rid == 72)      rhs = (double)pt[i];
    else if (rid < 36)  rhs = (s == rid) ? 1.0 : 0.0;
    else                rhs = (t == rid - 36) ? 1.0 : 0.0;
    xl[k] = 0.0; rl[k] = rhs; pv[i] = rhs;
  }
  __syncthreads();

  double loc = 0.0;
#pragma unroll
  for (int k = 0; k < PERTHREAD; ++k) {
    int i = tid + 256 * k;
    if (i < NN2) loc += rl[k] * rl[k];
  }
  double rr = blk_reduce(loc, red, &s_rr);
  const double rr0 = rr;

  for (int it = 0; it < CGMAX; ++it) {
    if (tid < NNODE) {
      double r0 = 0.0, wr0 = 0.0;
      for (int s = 0; s < NNODE; ++s) {
        double v = pv[tid * NNODE + s];
        r0 += v; wr0 += (double)pt[tid * NNODE + s] * v;
      }
      R[tid] = r0; WR[tid] = wr0;
    } else if (tid < 2 * NNODE) {
      int s = tid - NNODE;
      double c0 = 0.0, wc0 = 0.0;
      for (int t = 0; t < NNODE; ++t) {
        double v = pv[t * NNODE + s];
        c0 += v; wc0 += (double)pt[t * NNODE + s] * v;
      }
      C[s] = c0; WC[s] = wc0;
    }
    __syncthreads();
    if (tid == 0) {
      double tt = 0.0, wt = 0.0;
      for (int t = 0; t < NNODE; ++t) { tt += R[t]; wt += WR[t]; }
      totW[0] = tt; totW[1] = wt;
    }
    __syncthreads();

    double locpap = 0.0;
#pragma unroll
    for (int k = 0; k < PERTHREAD; ++k) {
      int i = tid + 256 * k;
      if (i >= NN2) break;
      int t = i / NNODE, s = i % NNODE;
      double pval = pv[i], ptv = (double)pt[i];
      double sig1 = totW[0] - R[t] - C[s] + pval;
      double sig2 = totW[1] - WR[t] - WC[s] + ptv * pval;
      double q = KDIAG * pval - 0.5 * (ptv * sig1 + sig2);
      al[k] = q;
      locpap += pval * q;
    }
    double pap = blk_reduce(locpap, red, &s_pap);
    double alpha = rr / pap;

    double locrr = 0.0;
#pragma unroll
    for (int k = 0; k < PERTHREAD; ++k) {
      int i = tid + 256 * k;
      if (i >= NN2) break;
      xl[k] += alpha * pv[i];
      double rn = rl[k] - alpha * al[k];
      rl[k] = rn;
      locrr += rn * rn;
    }
    double rrn = blk_reduce(locrr, red, &s_rr);
    double beta = rrn / rr;
    rr = rrn;
    if (rr < 1e-18 * rr0 || rr < 1e-30) break;   // block-uniform exit
#pragma unroll
    for (int k = 0; k < PERTHREAD; ++k) {
      int i = tid + 256 * k;
      if (i < NN2) pv[i] = rl[k] + beta * pv[i];
    }
    __syncthreads();
  }

  if (rid == 72) {
#pragma unroll
    for (int k = 0; k < PERTHREAD; ++k) {
      int i = tid + 256 * k;
      if (i < NN2) Y[b * NN2 + i] = xl[k];
    }
  } else {
#pragma unroll
    for (int k = 0; k < PERTHREAD; ++k) {
      int i = tid + 256 * k;
      if (i < NN2) Z[((size_t)b * NC + rid) * NN2 + i] = (float)xl[k];
    }
  }

  // ---- epilogue: A*x -> Schur column (or A*y - 1 for rid==72) ----
  __syncthreads();
#pragma unroll
  for (int k = 0; k < PERTHREAD; ++k) {
    int i = tid + 256 * k;
    if (i < NN2) pv[i] = xl[k];
  }
  __syncthreads();
  if (tid < NNODE) {                 // S rows 36..71: first-index (row) sums
    double r0 = 0.0;
    for (int s = 0; s < NNODE; ++s) r0 += pv[tid * NNODE + s];
    if (rid == 72) r0 -= 1.0;
    Scols[((size_t)b * 73 + rid) * NC + NNODE + tid] = r0;
  } else if (tid < 2 * NNODE) {      // S rows 0..35: second-index (col) sums
    int s = tid - NNODE;
    double c0 = 0.0;
    for (int t = 0; t < NNODE; ++t) c0 += pv[t * NNODE + s];
    if (rid == 72) c0 -= 1.0;
    Scols[((size_t)b * 73 + rid) * NC + s] = c0;
  }
}

// ---------------------------------------------------------------------------
// Kernel 3 (replaces Cholesky k_chol + k_xout): per batch,
// CG on (symmetrized) S + eps*I for lambda, then x = y - Z*lambda, clamp,
// out = softmax(1000*x^T).
// Why CG: S|_{w-perp} has provable spectrum [36/1825, 72/625] (kappa<=5.9,
// Gershgorin on Q + eigencheck of A*A^T), rhs is exactly w-orthogonal
// (colsum-total == rowsum-total), so ~27 iters reach rel-res 1e-10. This
// removes the 72-step factorization + 144-step trisolves whose serial
// dependency chains cost 113-189 us in rounds 7/9.
// lambda/r/ap live in owner-thread registers (tid<72); only p is in LDS.
// ---------------------------------------------------------------------------
__global__ __launch_bounds__(256) void k_schur_out(const double* __restrict__ Scols,
                                                   const float* __restrict__ Z,
                                                   const double* __restrict__ Y,
                                                   float* __restrict__ out) {
  const int b = blockIdx.x;
  const int tid = threadIdx.x;
  __shared__ double Sm[NC * SROW];   // padded rows: stride 73 doubles
  __shared__ double pvs[NC];
  __shared__ double lamLDS[NC];
  __shared__ double red[4], s_pap, s_rr;
  __shared__ float xm[NN2];
  __shared__ float mrow[NNODE], irow[NNODE];

  const double* Sb = Scols + (size_t)b * 73 * NC;

  // load S symmetrized: Sm[i][j] = 0.5*(S[i][j] + S[j][i]) + eps on diag
  for (int o = tid; o < NC * NC; o += 256) {
    int i = o / NC, j = o % NC;
    double v = 0.5 * (Sb[(size_t)j * NC + i] + Sb[(size_t)i * NC + j]);
    if (i == j) v += EPSK;
    Sm[i * SROW + j] = v;
  }

  double lam = 0.0, rv = 0.0, ap = 0.0;
  if (tid < NC) {
    rv = Sb[(size_t)72 * NC + tid];  // rhs = A*y - 1
    pvs[tid] = rv;
  }
  __syncthreads();

  double rr = blk_reduce(tid < NC ? rv * rv : 0.0, red, &s_rr);
  const double rr0 = rr;

  for (int it = 0; it < CGSMAX; ++it) {
    // ap = S*p (owner rows); pap
    double locpap = 0.0;
    if (tid < NC) {
      double a = 0.0;
      const double* row = Sm + tid * SROW;
      for (int j = 0; j < NC; ++j) a += row[j] * pvs[j];
      ap = a;
      locpap = pvs[tid] * a;
    }
    double pap = blk_reduce(locpap, red, &s_pap);
    double alpha = rr / pap;

    double locrr = 0.0;
    if (tid < NC) {
      lam += alpha * pvs[tid];
      rv -= alpha * ap;
      locrr = rv * rv;
    }
    double rrn = blk_reduce(locrr, red, &s_rr);
    double beta = rrn / rr;
    rr = rrn;
    if (rr < 1e-20 * rr0 || rr < 1e-28) break;   // block-uniform exit
    if (tid < NC) pvs[tid] = rv + beta * pvs[tid];
    __syncthreads();
  }

  if (tid < NC) lamLDS[tid] = lam;
  __syncthreads();

  // x = y - Z*lambda (coalesced over j), clamp to [0,1]
  const float* Zb = Z + (size_t)b * NC * NN2;
  const double* yb = Y + (size_t)b * NN2;
  for (int i = tid; i < NN2; i += 256) {
    double acc = yb[i];
#pragma unroll 8
    for (int j = 0; j < NC; ++j) acc -= (double)Zb[j * NN2 + i] * lamLDS[j];
    float v = (float)acc;
    xm[i] = fminf(fmaxf(v, 0.f), 1.f);
  }
  __syncthreads();

  // per-output-row i: max and softmax denominator over j (column i of xm)
  if (tid < NNODE) {
    float m = -1e30f;
    for (int j = 0; j < NNODE; ++j) m = fmaxf(m, xm[j * NNODE + tid]);
    float sum = 0.f;
    for (int j = 0; j < NNODE; ++j) sum += expf(1000.f * (xm[j * NNODE + tid] - m));
    mrow[tid] = m;
    irow[tid] = 1.f / sum;
  }
  __syncthreads();

  for (int o = tid; o < NN2; o += 256) {
    int i = o / NNODE, j = o % NNODE;
    out[(size_t)b * NN2 + o] = expf(1000.f * (xm[j * NNODE + i] - mrow[i])) * irow[i];
  }
}

// ---------------------------------------------------------------------------
extern "C" void kernel_launch(void* const* d_in, const int* in_sizes, int n_in,
                              void* d_out, int out_size, void* d_ws, size_t ws_size,
                              hipStream_t stream) {
  (void)in_sizes; (void)n_in; (void)out_size; (void)ws_size;
  const float* emb1 = (const float*)d_in[0];
  const float* emb2 = (const float*)d_in[1];
  const float* Wcg  = (const float*)d_in[2];
  const float* bcg  = (const float*)d_in[3];
  float* out = (float*)d_out;

  char* ws = (char*)d_ws;
  float*  PT    = (float*) (ws);                 // 8*1296 f32          = 41472 B
  float*  Z     = (float*) (ws + 41472);         // 8*72*1296 f32       = 2985984 B
  double* Y     = (double*)(ws + 3027456);       // 8*1296 f64          = 82944 B
  double* Scols = (double*)(ws + 3110400);       // 8*73*72 f64         = 336384 B

  hipLaunchKernelGGL(k_feat_p,    dim3(NB),      dim3(256), 0, stream, emb1, emb2, Wcg, bcg, PT);
  hipLaunchKernelGGL(k_cg,        dim3(NB * 73), dim3(256), 0, stream, PT, Z, Y, Scols);
  hipLaunchKernelGGL(k_schur_out, dim3(NB),      dim3(256), 0, stream, Scols, Z, Y, out);
}

// Round 13
// 113.279 us; speedup vs baseline: 2.9001x; 1.2727x over previous
//
#include <hip/hip_runtime.h>
#include <math.h>

// Problem constants (B=8, N=36, D=64)
#define NB    8
#define NNODE 36
#define NN2   1296     // 36*36
#define ND    64
#define KD    1225.0   // (N-1)^2
#define EPSK  1e-5
#define PTR   6        // ceil(1296/256) elems per thread
#define PCGMAX 48

// ---------------------------------------------------------------------------
// Block-wide fp64 reductions (256 threads = 4 waves of 64)
// ---------------------------------------------------------------------------
__device__ __forceinline__ double blk_reduce(double v, double* red, double* out) {
#pragma unroll
  for (int off = 32; off > 0; off >>= 1) v += __shfl_down(v, off);
  if ((threadIdx.x & 63) == 0) red[threadIdx.x >> 6] = v;
  __syncthreads();
  if (threadIdx.x == 0) *out = red[0] + red[1] + red[2] + red[3];
  __syncthreads();
  return *out;
}

__device__ __forceinline__ void blk_reduce2(double a, double b, double* redA,
                                            double* redB, double* out2) {
#pragma unroll
  for (int off = 32; off > 0; off >>= 1) {
    a += __shfl_down(a, off);
    b += __shfl_down(b, off);
  }
  if ((threadIdx.x & 63) == 0) {
    redA[threadIdx.x >> 6] = a;
    redB[threadIdx.x >> 6] = b;
  }
  __syncthreads();
  if (threadIdx.x == 0) {
    out2[0] = redA[0] + redA[1] + redA[2] + redA[3];
    out2[1] = redB[0] + redB[1] + redB[2] + redB[3];
  }
  __syncthreads();
}

// ---------------------------------------------------------------------------
// ONE fused kernel per batch (8 blocks x 256 threads), fully LDS-resident:
//  1. feat: normalize over node axis, linear(W,b), relu, PT = Mp^T (fp32,
//     matches reference fp32 arithmetic) — verified round-5 code.
//  2. Penalty-PCG: the reference KKT with dual regularization -eps*I is
//     EXACTLY the penalty system  (Q + sig*A^T A) x = q + sig*A^T 1,
//     sig = 1/eps  (eliminate lambda = (Ax-1)/eps — exact algebra).
//     Q x = 1225x - Mx with the O(n^2) structured matvec;
//     (A^T A X)[t,s] = R(X)[t] + C(X)[s]  (closed form).
//     Preconditioner M = c*I + sig*A^T A, c = 1225, inverted in closed form:
//       M^-1 z = (z + aM*(Rz[t]+Cz[s]) + gM*sum(z)) / c,
//       aM = -sig/(c+36sig), gM = -2*aM*sig/(c+72sig)
//     (verified on all three A^T A eigenspaces). spec(M^-1 K) in [1-rho,1+rho],
//     rho = ||M_aff||/1225 ~ 0.5 -> kappa <= 3 -> ~15-19 iters.
//     x0 = J/36 (feasible: the sigma terms cancel exactly in r0).
//  3. clamp, alpha=1000 transposed softmax, write out — verified round-12 code.
// Replaces: k_cg (584 blocks), k_schur_out, Z (2.9MB), Scols — and 2 launches.
// ---------------------------------------------------------------------------
__global__ __launch_bounds__(256) void k_fused(const float* __restrict__ emb1,
                                               const float* __restrict__ emb2,
                                               const float* __restrict__ Wcg,
                                               const float* __restrict__ bcg,
                                               float* __restrict__ out) {
  const int b = blockIdx.x;
  const int tid = threadIdx.x;

  // ---- phase-aliased LDS: pt persists; feat area is reused by PCG ----
  __shared__ __align__(16) char smem[58944];
  float* pt = (float*)smem;                    // [1296] persists
  char* ph = smem + 5184;
  // feat view (53760 B)
  float* e1 = (float*)ph;                      // 2304
  float* e2 = e1 + 2304;                       // 2304
  float* h1 = e2 + 2304;                       // 2304
  float* h2 = h1 + 2304;                       // 2304
  float* Ws = h2 + 2304;                       // 4096
  float* nrm1 = Ws + 4096;                     // 64
  float* nrm2 = nrm1 + 64;                     // 64
  // PCG view (28064 B)
  double* pbuf = (double*)ph;                  // 1296
  double* rbuf = pbuf + 1296;                  // 1296
  double* Rp = rbuf + 1296;                    // 36
  double* Cp = Rp + 36;
  double* WRp = Cp + 36;
  double* WCp = WRp + 36;
  double* Rr = WCp + 36;
  double* Cr = Rr + 36;
  double* red  = Cr + 36;                      // 4
  double* red2 = red + 4;                      // 4
  double* sc   = red2 + 4;                     // 8 scalars
  float* xm  = (float*)(sc + 8);               // 1296 (after rbuf+sums region)
  float* mrow = xm + 1296;                     // 36
  float* irow = mrow + 36;                     // 36

  // ========================= 1. feat (verified) ============================
  for (int i = tid; i < NNODE * ND; i += 256) {
    e1[i] = emb1[b * NNODE * ND + i];
    e2[i] = emb2[b * NNODE * ND + i];
  }
  for (int i = tid; i < ND * ND; i += 256) Ws[i] = Wcg[i];
  __syncthreads();

  if (tid < ND) {
    float s = 0.f;
    for (int n = 0; n < NNODE; ++n) { float v = e1[n * ND + tid]; s += v * v; }
    nrm1[tid] = fmaxf(sqrtf(s), 1e-12f);
  } else if (tid < 2 * ND) {
    int d = tid - ND;
    float s = 0.f;
    for (int n = 0; n < NNODE; ++n) { float v = e2[n * ND + d]; s += v * v; }
    nrm2[d] = fmaxf(sqrtf(s), 1e-12f);
  }
  __syncthreads();

  for (int i = tid; i < NNODE * ND; i += 256) {
    int d = i & (ND - 1);
    e1[i] /= nrm1[d];
    e2[i] /= nrm2[d];
  }
  __syncthreads();

  for (int o = tid; o < NNODE * ND; o += 256) {
    int n = o >> 6, i = o & (ND - 1);
    float a1 = bcg[i], a2 = bcg[i];
    for (int d = 0; d < ND; ++d) {
      float w = Ws[i * ND + d];
      a1 += e1[n * ND + d] * w;
      a2 += e2[n * ND + d] * w;
    }
    h1[o] = fmaxf(a1, 0.f);
    h2[o] = fmaxf(a2, 0.f);
  }
  __syncthreads();

  for (int o = tid; o < NN2; o += 256) {
    int t = o / NNODE, s = o % NNODE;
    float a = 0.f;
    for (int d = 0; d < ND; ++d) a += h1[s * ND + d] * h2[t * ND + d];
    pt[o] = a;                                 // q[t,s] = Mp[s,t] (fp32)
  }
  __syncthreads();  // pt complete; feat area may now be reused

  // ========================= 2. penalty-PCG ================================
  const double SIG = 1.0 / EPSK;
  const double cM = KD;
  const double aM = -SIG / (cM + 36.0 * SIG);
  const double gM = -2.0 * aM * SIG / (cM + 72.0 * SIG);

  double xl[PTR], rl[PTR], zl[PTR], wl[PTR], pl[PTR];

  // p = x0 = 1/36 (feasible); local totals (sum p, sum pt*p)
  double la = 0.0, lb = 0.0;
#pragma unroll
  for (int k = 0; k < PTR; ++k) {
    int i = tid + 256 * k;
    if (i < NN2) {
      xl[k] = 1.0 / 36.0;
      pl[k] = 1.0 / 36.0;
      pbuf[i] = 1.0 / 36.0;
      la += 1.0 / 36.0;
      lb += (double)pt[i] * (1.0 / 36.0);
    }
  }
  blk_reduce2(la, lb, red, red2, sc);          // publishes pbuf too
  double totp = sc[0], wtotp = sc[1];

  // row/col sums of p
  if (tid < NNODE) {
    double r0 = 0.0, wr0 = 0.0;
    for (int s = 0; s < NNODE; ++s) {
      double v = pbuf[tid * NNODE + s];
      r0 += v; wr0 += (double)pt[tid * NNODE + s] * v;
    }
    Rp[tid] = r0; WRp[tid] = wr0;
  } else if (tid < 2 * NNODE) {
    int s = tid - NNODE;
    double c0 = 0.0, wc0 = 0.0;
    for (int t = 0; t < NNODE; ++t) {
      double v = pbuf[t * NNODE + s];
      c0 += v; wc0 += (double)pt[t * NNODE + s] * v;
    }
    Cp[s] = c0; WCp[s] = wc0;
  }
  __syncthreads();

  // r0 = q + 2*SIG - K*x0 ; local (rr, tot r)
  la = 0.0; lb = 0.0;
#pragma unroll
  for (int k = 0; k < PTR; ++k) {
    int i = tid + 256 * k;
    if (i < NN2) {
      int t = i / NNODE, s = i % NNODE;
      double pval = pl[k], ptv = (double)pt[i];
      double sig1 = totp - Rp[t] - Cp[s] + pval;
      double sig2 = wtotp - WRp[t] - WCp[s] + ptv * pval;
      double w = KD * pval - 0.5 * (ptv * sig1 + sig2) + SIG * (Rp[t] + Cp[s]);
      double r = ptv + 2.0 * SIG - w;
      rl[k] = r; rbuf[i] = r;
      la += r * r; lb += r;
    }
  }
  blk_reduce2(la, lb, red, red2, sc);
  double rr = sc[0], totr = sc[1];
  const double rr0 = rr;

  // sums of r
  if (tid < NNODE) {
    double r0 = 0.0;
    for (int s = 0; s < NNODE; ++s) r0 += rbuf[tid * NNODE + s];
    Rr[tid] = r0;
  } else if (tid < 2 * NNODE) {
    int s = tid - NNODE;
    double c0 = 0.0;
    for (int t = 0; t < NNODE; ++t) c0 += rbuf[t * NNODE + s];
    Cr[s] = c0;
  }
  __syncthreads();

  // z = M^-1 r ; rz
  la = 0.0;
#pragma unroll
  for (int k = 0; k < PTR; ++k) {
    int i = tid + 256 * k;
    if (i < NN2) {
      int t = i / NNODE, s = i % NNODE;
      double z = (rl[k] + aM * (Rr[t] + Cr[s]) + gM * totr) / cM;
      zl[k] = z;
      la += z * rl[k];
    }
  }
  double rz = blk_reduce(la, red, sc + 2);

  // p = z (beta=0); totals
  la = 0.0; lb = 0.0;
#pragma unroll
  for (int k = 0; k < PTR; ++k) {
    int i = tid + 256 * k;
    if (i < NN2) {
      pl[k] = zl[k]; pbuf[i] = zl[k];
      la += zl[k]; lb += (double)pt[i] * zl[k];
    }
  }
  blk_reduce2(la, lb, red, red2, sc);
  totp = sc[0]; wtotp = sc[1];

  // ---- main PCG loop ----
  for (int it = 0; it < PCGMAX; ++it) {
    // A: row/col sums of p
    if (tid < NNODE) {
      double r0 = 0.0, wr0 = 0.0;
      for (int s = 0; s < NNODE; ++s) {
        double v = pbuf[tid * NNODE + s];
        r0 += v; wr0 += (double)pt[tid * NNODE + s] * v;
      }
      Rp[tid] = r0; WRp[tid] = wr0;
    } else if (tid < 2 * NNODE) {
      int s = tid - NNODE;
      double c0 = 0.0, wc0 = 0.0;
      for (int t = 0; t < NNODE; ++t) {
        double v = pbuf[t * NNODE + s];
        c0 += v; wc0 += (double)pt[t * NNODE + s] * v;
      }
      Cp[s] = c0; WCp[s] = wc0;
    }
    __syncthreads();

    // B: w = K p ; pap
    la = 0.0;
#pragma unroll
    for (int k = 0; k < PTR; ++k) {
      int i = tid + 256 * k;
      if (i < NN2) {
        int t = i / NNODE, s = i % NNODE;
        double pval = pl[k], ptv = (double)pt[i];
        double sig1 = totp - Rp[t] - Cp[s] + pval;
        double sig2 = wtotp - WRp[t] - WCp[s] + ptv * pval;
        double w = KD * pval - 0.5 * (ptv * sig1 + sig2) + SIG * (Rp[t] + Cp[s]);
        wl[k] = w;
        la += pval * w;
      }
    }
    double pap = blk_reduce(la, red, sc + 3);
    double alpha = rz / pap;

    // C: x += a p ; r -= a w ; (rr, tot r)
    la = 0.0; lb = 0.0;
#pragma unroll
    for (int k = 0; k < PTR; ++k) {
      int i = tid + 256 * k;
      if (i < NN2) {
        xl[k] += alpha * pl[k];
        double r = rl[k] - alpha * wl[k];
        rl[k] = r; rbuf[i] = r;
        la += r * r; lb += r;
      }
    }
    blk_reduce2(la, lb, red, red2, sc);
    rr = sc[0]; totr = sc[1];
    if (rr < 1e-16 * rr0 || rr < 1e-26) break;   // block-uniform

    // D: row/col sums of r
    if (tid < NNODE) {
      double r0 = 0.0;
      for (int s = 0; s < NNODE; ++s) r0 += rbuf[tid * NNODE + s];
      Rr[tid] = r0;
    } else if (tid < 2 * NNODE) {
      int s = tid - NNODE;
      double c0 = 0.0;
      for (int t = 0; t < NNODE; ++t) c0 += rbuf[t * NNODE + s];
      Cr[s] = c0;
    }
    __syncthreads();

    // E: z = M^-1 r ; rz_new
    la = 0.0;
#pragma unroll
    for (int k = 0; k < PTR; ++k) {
      int i = tid + 256 * k;
      if (i < NN2) {
        int t = i / NNODE, s = i % NNODE;
        double z = (rl[k] + aM * (Rr[t] + Cr[s]) + gM * totr) / cM;
        zl[k] = z;
        la += z * rl[k];
      }
    }
    double rznew = blk_reduce(la, red, sc + 2);
    double beta = rznew / rz;
    rz = rznew;

    // F: p = z + beta p ; totals
    la = 0.0; lb = 0.0;
#pragma unroll
    for (int k = 0; k < PTR; ++k) {
      int i = tid + 256 * k;
      if (i < NN2) {
        double p = zl[k] + beta * pl[k];
        pl[k] = p; pbuf[i] = p;
        la += p; lb += (double)pt[i] * p;
      }
    }
    blk_reduce2(la, lb, red, red2, sc);
    totp = sc[0]; wtotp = sc[1];
  }

  // ========================= 3. clamp + softmax + out ======================
#pragma unroll
  for (int k = 0; k < PTR; ++k) {
    int i = tid + 256 * k;
    if (i < NN2) {
      float v = (float)xl[k];
      xm[i] = fminf(fmaxf(v, 0.f), 1.f);
    }
  }
  __syncthreads();

  if (tid < NNODE) {
    float m = -1e30f;
    for (int j = 0; j < NNODE; ++j) m = fmaxf(m, xm[j * NNODE + tid]);
    float sum = 0.f;
    for (int j = 0; j < NNODE; ++j) sum += expf(1000.f * (xm[j * NNODE + tid] - m));
    mrow[tid] = m;
    irow[tid] = 1.f / sum;
  }
  __syncthreads();

  for (int o = tid; o < NN2; o += 256) {
    int i = o / NNODE, j = o % NNODE;
    out[(size_t)b * NN2 + o] = expf(1000.f * (xm[j * NNODE + i] - mrow[i])) * irow[i];
  }
}

// ---------------------------------------------------------------------------
extern "C" void kernel_launch(void* const* d_in, const int* in_sizes, int n_in,
                              void* d_out, int out_size, void* d_ws, size_t ws_size,
                              hipStream_t stream) {
  (void)in_sizes; (void)n_in; (void)out_size; (void)d_ws; (void)ws_size;
  const float* emb1 = (const float*)d_in[0];
  const float* emb2 = (const float*)d_in[1];
  const float* Wcg  = (const float*)d_in[2];
  const float* bcg  = (const float*)d_in[3];
  float* out = (float*)d_out;

  hipLaunchKernelGGL(k_fused, dim3(NB), dim3(256), 0, stream,
                     emb1, emb2, Wcg, bcg, out);
}